// Round 22
// baseline (221.349 us; speedup 1.0000x reference)
//
#include <hip/hip_runtime.h>
#include <hip/hip_bf16.h>
#include <math.h>

// Problem constants (match reference)
#define RR 10
#define BB 8
#define NN 8192
#define HH 8
#define BN 65536            // BB*NN nodes per ROI
#define EE (1u << 20)       // directed edges per ROI = 2*B*EPAIR
#define EPB (EE / BB)       // 131072 directed edges per (ROI,patient), contiguous
#define NPAIR (EPB / 2)     // 65536 undirected pairs per (r,b)
#define KK 4096             // TopKPooling keeps K of NN
#define NSUP 80             // B*R super nodes
#define CSRL4 34816         // LDS CSR slots per QUARTER: mean 32768, sigma~157 -> +13 sigma

#define NTL(p) __builtin_nontemporal_load(p)
typedef int vi4 __attribute__((ext_vector_type(4)));   // clang vector: valid for nontemporal builtin

// ---------------- k1: per-(rb, node-EIGHTH) in-degree count + rank (uchar) + z = x*dis ----------------
// vi4 edge loads (lane l owns edges 4l..4l+3: 16B/lane coalesced). Rank stores stay
// byte-conditional (bytes interleave across the 8 concurrent eighth-blocks of one rb).
__global__ __launch_bounds__(1024)
void count_kernel(const int* __restrict__ ei, const float* __restrict__ x,
                  unsigned char* __restrict__ rankg,
                  unsigned short* __restrict__ qo8g, int* __restrict__ et8g,
                  float* __restrict__ zg) {
  const int bid = blockIdx.x;
  const int rb = bid % 80;
  const int p = bid / 80;                 // node eighth 0..7
  const int r = rb / BB;
  const int b = rb % BB;
  const int tid = threadIdx.x;

  __shared__ int scnt[1024];
  __shared__ int ps[1024];
  scnt[tid] = 0;
  __syncthreads();

  const int* up = ei + (size_t)r * 2u * EE + (size_t)b * EPB;        // pair u side
  const int* vp = ei + (size_t)r * 2u * EE + EE + (size_t)b * EPB;   // pair v side
  unsigned char* rk = rankg + (size_t)rb * EPB;

#define CNT(U, V, E)                                                \
  {                                                                 \
    int lv = (V) & (NN - 1);                                        \
    if ((lv >> 10) == p) {                                          \
      int t0 = atomicAdd(&scnt[lv & 1023], 1);                      \
      rk[E] = (unsigned char)t0;                                    \
    }                                                               \
    int lu = (U) & (NN - 1);                                        \
    if ((lu >> 10) == p) {                                          \
      int t1 = atomicAdd(&scnt[lu & 1023], 1);                      \
      rk[(E) + NPAIR] = (unsigned char)t1;                          \
    }                                                               \
  }
#pragma unroll 4
  for (int it = 0; it < 16; ++it) {
    int e = it * 4096 + tid * 4;
    vi4 uu = NTL((const vi4*)(up + e));
    vi4 vv = NTL((const vi4*)(vp + e));
    CNT(uu.x, vv.x, e) CNT(uu.y, vv.y, e + 1)
    CNT(uu.z, vv.z, e + 2) CNT(uu.w, vv.w, e + 3)
  }
#undef CNT
  __syncthreads();

  // inclusive scan over this eighth's 1024 counts (1 element/thread)
  int a = scnt[tid];
  ps[tid] = a;
  __syncthreads();
  for (int s2 = 1; s2 < 1024; s2 <<= 1) {
    int v = 0;
    if (tid >= s2) v = ps[tid - s2];
    __syncthreads();
    ps[tid] += v;
    __syncthreads();
  }
  int incl = ps[tid];
  qo8g[(size_t)rb * 8192 + (size_t)p * 1024 + tid] = (unsigned short)(incl - a);
  if (tid == 1023) et8g[rb * 8 + p] = incl;

  // z tail: z[n] = x[n] * rsqrt(deg+1)
  {
    int n = p * 1024 + tid;
    const float4* x4 = (const float4*)x + (size_t)r * BN + (size_t)b * NN;
    float4* z4 = (float4*)zg + (size_t)rb * NN;
    float ds = rsqrtf((float)a + 1.0f);
    float4 xv = x4[n];
    z4[n] = make_float4(xv.x * ds, xv.y * ds, xv.z * ds, xv.w * ds);
  }
}

// ---------------- k2: per-(rb, node-QUARTER) LDS-CSR scatter + z-pull + fused GCN epilogue ----------------
// vi4 edge loads + u32 rank loads (reads race-free). Scatter via rank: zero atomics.
__global__ __launch_bounds__(1024)
void scatfuse_kernel(const int* __restrict__ ei, const float* __restrict__ zg,
                     const unsigned char* __restrict__ rankg,
                     const unsigned short* __restrict__ qo8g, const int* __restrict__ et8g,
                     const float* __restrict__ gcn_w, const float* __restrict__ gcn_b,
                     const float* __restrict__ ln_w, const float* __restrict__ topk_w,
                     float* __restrict__ v4g, float* __restrict__ tg,
                     double* __restrict__ partsS, float* __restrict__ partsC) {
  const int bid = blockIdx.x;
  const int rb = bid % 80;
  const int q = bid / 80;                  // node quarter 0..3
  const int r = rb / BB;
  const int b = rb % BB;
  const int tid = threadIdx.x;

  __shared__ unsigned short qoQ[2049];                 // quarter-local offsets (+sentinel)
  __shared__ __align__(16) unsigned short csrL[CSRL4]; // 69.6 KB -> ~74KB total, 2 blk/CU
  __shared__ int etq[2];

  if (tid < 2) etq[tid] = et8g[rb * 8 + q * 2 + tid];
  __syncthreads();
  const unsigned short* qo8 = qo8g + (size_t)rb * 8192 + (size_t)q * 2048;
  for (int i = tid; i < 2048; i += 1024)
    qoQ[i] = (unsigned short)((int)qo8[i] + ((i >= 1024) ? etq[0] : 0));
  if (tid == 0) qoQ[2048] = (unsigned short)(etq[0] + etq[1]);
  __syncthreads();

  const int* up = ei + (size_t)r * 2u * EE + (size_t)b * EPB;
  const int* vp = ei + (size_t)r * 2u * EE + EE + (size_t)b * EPB;
  const unsigned char* rk = rankg + (size_t)rb * EPB;

#define SCAT(U, V, RA, RB2)                                         \
  {                                                                 \
    int lv = (V) & (NN - 1);                                        \
    if ((lv >> 11) == q) {                                          \
      csrL[(int)qoQ[lv & 2047] + (int)(RA)] =                       \
          (unsigned short)((U) & (NN - 1));                         \
    }                                                               \
    int lu = (U) & (NN - 1);                                        \
    if ((lu >> 11) == q) {                                          \
      csrL[(int)qoQ[lu & 2047] + (int)(RB2)] =                      \
          (unsigned short)((V) & (NN - 1));                         \
    }                                                               \
  }
#pragma unroll 4
  for (int it = 0; it < 16; ++it) {
    int e = it * 4096 + tid * 4;
    unsigned ra = NTL((const unsigned*)(rk + e));           // ranks dirs u->v, edges e..e+3
    unsigned rbv = NTL((const unsigned*)(rk + NPAIR + e));  // ranks dirs v->u
    vi4 uu = NTL((const vi4*)(up + e));
    vi4 vv = NTL((const vi4*)(vp + e));
    SCAT(uu.x, vv.x, ra & 255u, rbv & 255u)
    SCAT(uu.y, vv.y, (ra >> 8) & 255u, (rbv >> 8) & 255u)
    SCAT(uu.z, vv.z, (ra >> 16) & 255u, (rbv >> 16) & 255u)
    SCAT(uu.w, vv.w, (ra >> 24) & 255u, (rbv >> 24) & 255u)
  }
#undef SCAT
  __syncthreads();

  // per-r constants (wave-uniform -> scalar loads)
  const float* wp = gcn_w + r * 32;
  const float* bgp = gcn_b + r * 8;
  float lwwt[8];
#pragma unroll
  for (int c = 0; c < 8; ++c) lwwt[c] = ln_w[r * 8 + c] * topk_w[r * 8 + c];

  const float4* z4 = (const float4*)zg + (size_t)rb * NN;
  float4* v4o = (float4*)v4g + (size_t)rb * NN;
  float* trow = tg + (size_t)rb * NN;

  double s1 = 0.0, s2 = 0.0;
  float ch[8] = {0, 0, 0, 0, 0, 0, 0, 0};

#pragma unroll
  for (int k = 0; k < 2; ++k) {
    int idx = tid + k * 1024;             // index within quarter
    int n = q * 2048 + idx;               // local node id
    int o = (int)qoQ[idx];
    int c = (int)qoQ[idx + 1] - o;
    float4 zn = z4[n];                    // own z (coalesced)
    float sx = zn.x, sy = zn.y, sz = zn.z, sw = zn.w;   // self-term seed
    int j = 0;
    for (; j + 3 < c; j += 4) {
      int n0 = csrL[o + j], n1 = csrL[o + j + 1], n2 = csrL[o + j + 2], n3 = csrL[o + j + 3];
      float4 a0 = z4[n0], a1 = z4[n1], a2 = z4[n2], a3 = z4[n3];
      sx += a0.x + a1.x + a2.x + a3.x;
      sy += a0.y + a1.y + a2.y + a3.y;
      sz += a0.z + a1.z + a2.z + a3.z;
      sw += a0.w + a1.w + a2.w + a3.w;
    }
    for (; j < c; ++j) {
      int n0 = csrL[o + j];
      float4 a0 = z4[n0];
      sx += a0.x; sy += a0.y; sz += a0.z; sw += a0.w;
    }
    float dd = rsqrtf((float)c + 1.0f);
    float v0 = sx * dd, v1 = sy * dd, v2 = sz * dd, v3 = sw * dd;
    v4o[n] = make_float4(v0, v1, v2, v3);
    float t = 0.f;
#pragma unroll
    for (int cc = 0; cc < 8; ++cc) {
      float h = fmaxf(v0 * wp[cc] + v1 * wp[8 + cc] + v2 * wp[16 + cc] + v3 * wp[24 + cc] + bgp[cc], 0.0f);
      s1 += h;
      s2 += (double)h * h;
      ch[cc] += h;
      t += h * lwwt[cc];
    }
    trow[n] = t;
  }

  // block-reduce partials; reuse csrL as scratch (done with CSR)
  __syncthreads();
  double* wredS = (double*)csrL;              // 16 x 2 doubles @ 0
  float* wredC = (float*)(csrL + 512);        // 16 x 8 floats @ +1024B
  int lane = tid & 63, wid = tid >> 6;
#pragma unroll
  for (int off = 32; off > 0; off >>= 1) {
    s1 += __shfl_down(s1, off);
    s2 += __shfl_down(s2, off);
#pragma unroll
    for (int cc = 0; cc < 8; ++cc) ch[cc] += __shfl_down(ch[cc], off);
  }
  if (lane == 0) {
    wredS[wid * 2] = s1;
    wredS[wid * 2 + 1] = s2;
#pragma unroll
    for (int cc = 0; cc < 8; ++cc) wredC[wid * 8 + cc] = ch[cc];
  }
  __syncthreads();
  if (tid == 0) {
    double a = 0.0, b3 = 0.0;
    for (int w2 = 0; w2 < 16; ++w2) { a += wredS[w2 * 2]; b3 += wredS[w2 * 2 + 1]; }
    partsS[bid * 2] = a;
    partsS[bid * 2 + 1] = b3;
  }
  if (tid < 8) {
    float sc = 0.f;
    for (int w2 = 0; w2 < 16; ++w2) sc += wredC[w2 * 8 + tid];
    partsC[bid * 8 + tid] = sc;
  }
}

// ---------------- k3: per-(r,b) stats combine + score + WAVE-PARALLEL radix-select + pools ----------------
__global__ __launch_bounds__(1024)
void roiB_kernel(const float* __restrict__ tg, const float* __restrict__ v4g,
                 const double* __restrict__ partsS, const float* __restrict__ partsC,
                 const float* __restrict__ gcn_w, const float* __restrict__ gcn_b,
                 const float* __restrict__ ln_w, const float* __restrict__ ln_b,
                 const float* __restrict__ topk_w, const float* __restrict__ cen,
                 float* __restrict__ feats) {
  const int rb = blockIdx.x;
  const int r = rb / BB;
  const int tid = threadIdx.x;
  const int lane = tid & 63, wid = tid >> 6;

  __shared__ int histW[16 * 256];     // wave-private histograms (16 KB)
  __shared__ int wtot[16];
  __shared__ float chS[8];
  __shared__ float fvSum[8];
  __shared__ int cntGt;
  __shared__ int selb, kleft;
  __shared__ float sstat[2];

  float lw[8], lb[8], wt[8], w[32], bg[8];
  float wn2 = 0.f, L1 = 0.f, B1 = 0.f;
#pragma unroll
  for (int i = 0; i < 32; ++i) w[i] = gcn_w[r * 32 + i];
#pragma unroll
  for (int c = 0; c < 8; ++c) {
    lw[c] = ln_w[r * 8 + c];
    lb[c] = ln_b[r * 8 + c];
    wt[c] = topk_w[r * 8 + c];
    bg[c] = gcn_b[r * 8 + c];
    wn2 += wt[c] * wt[c];
    L1 += lw[c] * wt[c];
    B1 += lb[c] * wt[c];
  }
  const float invn = 1.0f / sqrtf(wn2);

  if (tid == 0) {
    double s1 = 0.0, s2 = 0.0;
    for (int q = 0; q < 4; ++q) {
      s1 += partsS[(q * 80 + rb) * 2];
      s2 += partsS[(q * 80 + rb) * 2 + 1];
    }
    const double M = (double)NN * HH;
    double mu = s1 / M;
    double var = s2 / M - mu * mu;
    sstat[0] = (float)mu;
    sstat[1] = (float)(1.0 / sqrt(var + 1e-5));
    cntGt = 0;
  }
  if (tid < 8) {
    float sc = 0.f;
    for (int q = 0; q < 4; ++q) sc += partsC[(q * 80 + rb) * 8 + tid];
    chS[tid] = sc;
    fvSum[tid] = 0.f;
  }
  __syncthreads();
  const float muf = sstat[0];
  const float rstd = sstat[1];
  const float C0 = B1 - rstd * muf * L1;   // pre = rstd*t + C0

  const float* trow = tg + (size_t)rb * NN;
  float sv[8];
  unsigned fl[8];
#pragma unroll
  for (int i = 0; i < 8; ++i) {
    int n = tid * 8 + i;
    float s = tanhf((rstd * trow[n] + C0) * invn);
    sv[i] = s;
    unsigned u = __float_as_uint(s);
    fl[i] = (u & 0x80000000u) ? ~u : (u | 0x80000000u);  // monotonic flip
  }

  // Radix-select K-th largest (exact), 4 passes of 8 bits.
  unsigned prefix = 0;
  int kneed = KK;
  for (int shift = 24; shift >= 0; shift -= 8) {
#pragma unroll
    for (int z = 0; z < 4; ++z) histW[tid + z * 1024] = 0;
    __syncthreads();
#pragma unroll
    for (int i = 0; i < 8; ++i) {
      bool m = (shift == 24) || ((fl[i] >> (shift + 8)) == prefix);
      if (m) atomicAdd(&histW[wid * 256 + ((fl[i] >> shift) & 255)], 1);
    }
    __syncthreads();
    if (wid == 0) {
      // lane owns bins [4*lane .. 4*lane+3]; combine 16 wave-hists
      int b0 = lane * 4;
      int t0 = 0, t1 = 0, t2 = 0, t3 = 0;
      for (int w2 = 0; w2 < 16; ++w2) {
        const int* hp2 = &histW[w2 * 256 + b0];
        t0 += hp2[0]; t1 += hp2[1]; t2 += hp2[2]; t3 += hp2[3];
      }
      int s3 = t3, s2i = t2 + s3, s1i = t1 + s2i, s0 = t0 + s1i;  // in-lane suffix
      int v = s0;
#pragma unroll
      for (int off = 1; off < 64; off <<= 1) {
        int o = __shfl_down(v, off);
        v += (lane + off < 64) ? o : 0;           // v = sum over lanes >= lane
      }
      int above = v - s0;                          // = S[b0+4] (sum over bins >= b0+4)
      int S3 = above + s3, S2 = above + s2i, S1 = above + s1i, S0 = above + s0;
      // unique crossing bin: S[b] >= kneed > S[b+1]
      if (S3 >= kneed && above < kneed)      { selb = b0 + 3; kleft = kneed - above; }
      else if (S2 >= kneed && S3 < kneed)    { selb = b0 + 2; kleft = kneed - S3; }
      else if (S1 >= kneed && S2 < kneed)    { selb = b0 + 1; kleft = kneed - S2; }
      else if (S0 >= kneed && S1 < kneed)    { selb = b0;     kleft = kneed - S1; }
    }
    __syncthreads();
    prefix = (prefix << 8) | (unsigned)selb;
    kneed = kleft;
  }
  float tau = (prefix & 0x80000000u) ? __uint_as_float(prefix & 0x7fffffffu)
                                     : __uint_as_float(~prefix);

  // tie-break lowest-index-first: 2-level scan (wave shfl + 16 wave totals)
  int cg = 0, ct = 0;
#pragma unroll
  for (int i = 0; i < 8; ++i) {
    if (sv[i] > tau) cg++;
    else if (sv[i] == tau) ct++;
  }
  int wcg = cg;
#pragma unroll
  for (int off = 32; off > 0; off >>= 1) wcg += __shfl_down(wcg, off);
  if (lane == 0) atomicAdd(&cntGt, wcg);
  int sc = ct;
#pragma unroll
  for (int off = 1; off < 64; off <<= 1) {
    int o = __shfl_up(sc, off);
    if (lane >= off) sc += o;                      // inclusive scan within wave
  }
  if (lane == 63) wtot[wid] = sc;
  __syncthreads();
  int wbase = 0;
  for (int w2 = 0; w2 < wid; ++w2) wbase += wtot[w2];
  int rank = wbase + sc - ct;                      // exclusive tie-rank in block
  int quota = KK - cntGt;

  const float4* v4r = (const float4*)v4g + (size_t)rb * NN;
  float fva[8] = {0, 0, 0, 0, 0, 0, 0, 0};
#pragma unroll
  for (int i = 0; i < 8; ++i) {
    bool inc = sv[i] > tau;
    if (!inc && sv[i] == tau) { inc = (rank < quota); rank++; }
    if (inc) {
      int n = tid * 8 + i;
      float4 vv = v4r[n];
#pragma unroll
      for (int c = 0; c < 8; ++c) {
        float h = fmaxf(vv.x * w[c] + vv.y * w[8 + c] + vv.z * w[16 + c] + vv.w * w[24 + c] + bg[c], 0.0f);
        float hn = (h - muf) * rstd * lw[c] + lb[c];
        fva[c] += hn * sv[i];
      }
    }
  }
#pragma unroll
  for (int c = 0; c < 8; ++c) atomicAdd(&fvSum[c], fva[c]);
  __syncthreads();

  size_t fo = (size_t)rb * 19;
  if (tid < 8) {
    feats[fo + tid] = ((chS[tid] - (float)NN * muf) * rstd * lw[tid]) / (float)NN + lb[tid];
    feats[fo + 8 + tid] = fvSum[tid] / (float)KK;
  }
  if (tid >= 16 && tid < 19) {
    feats[fo + tid] = cen[(size_t)rb * 3 + (tid - 16)];
  }
}

// ---------------- super graph: GAT1 -> LN -> GAT2 -> LN -> pool -> linear ----------------
__global__ __launch_bounds__(256)
void super_kernel(const float* __restrict__ feats,
                  const float* __restrict__ W1, const float* __restrict__ as1,
                  const float* __restrict__ ad1, const float* __restrict__ b1,
                  const float* __restrict__ lnw1, const float* __restrict__ lnb1,
                  const float* __restrict__ W2, const float* __restrict__ as2,
                  const float* __restrict__ ad2, const float* __restrict__ b2,
                  const float* __restrict__ lnw2, const float* __restrict__ lnb2,
                  const float* __restrict__ linw, const float* __restrict__ linb,
                  float* __restrict__ out) {
  __shared__ float sx[NSUP * 19];
  __shared__ float h1[NSUP * 64];
  __shared__ float x1[NSUP * 64];
  __shared__ float es1[NSUP * 4], ed1[NSUP * 4];
  __shared__ float h2[NSUP * 16], x2[NSUP * 16];
  __shared__ float es2[NSUP], ed2[NSUP];
  __shared__ float stat[16];
  const int tid = threadIdx.x;

  for (int i = tid; i < NSUP * 19; i += 256) {
    int n = i / 19, c = i % 19;
    int bb = n / RR, rr = n % RR;
    sx[i] = feats[(size_t)(rr * BB + bb) * 19 + c];
  }
  __syncthreads();
  for (int p = tid; p < NSUP * 64; p += 256) {
    int n = p / 64, j = p % 64;
    float acc = 0.f;
    for (int k2 = 0; k2 < 19; ++k2) acc += sx[n * 19 + k2] * W1[k2 * 64 + j];
    h1[p] = acc;
  }
  __syncthreads();
  for (int p = tid; p < NSUP * 4; p += 256) {
    int n = p / 4, hd = p % 4;
    float a = 0.f, d2 = 0.f;
    for (int o = 0; o < 16; ++o) {
      float hv = h1[n * 64 + hd * 16 + o];
      a += hv * as1[hd * 16 + o];
      d2 += hv * ad1[hd * 16 + o];
    }
    es1[p] = a; ed1[p] = d2;
  }
  __syncthreads();
  for (int p = tid; p < NSUP * 64; p += 256) {
    int n = p / 64, j = p % 64, hd = j / 16;
    int rr = n % RR;
    float o;
    if (rr == 0) {
      o = h1[p];
    } else {
      int hub = n - rr;
      float eh = es1[hub * 4 + hd] + ed1[n * 4 + hd];
      float esf = es1[n * 4 + hd] + ed1[n * 4 + hd];
      eh = eh > 0.f ? eh : 0.2f * eh;
      esf = esf > 0.f ? esf : 0.2f * esf;
      float m = fmaxf(eh, esf);
      float wh = expf(eh - m), ws2 = expf(esf - m);
      o = (wh * h1[hub * 64 + j] + ws2 * h1[n * 64 + j]) / (wh + ws2);
    }
    float v = o + b1[j];
    x1[p] = v > 0.f ? v : expm1f(v);   // elu
  }
  __syncthreads();
  if (tid < BB) {
    double m = 0.0, v2 = 0.0;
    for (int q = 0; q < RR * 64; ++q) {
      float val = x1[tid * RR * 64 + q];
      m += val; v2 += (double)val * val;
    }
    m /= (RR * 64.0); v2 = v2 / (RR * 64.0) - m * m;
    stat[tid] = (float)m;
    stat[8 + tid] = (float)(1.0 / sqrt(v2 + 1e-5));
  }
  __syncthreads();
  for (int p = tid; p < NSUP * 64; p += 256) {
    int n = p / 64, j = p % 64, bb = n / RR;
    x1[p] = (x1[p] - stat[bb]) * stat[8 + bb] * lnw1[j] + lnb1[j];
  }
  __syncthreads();
  for (int p = tid; p < NSUP * 16; p += 256) {
    int n = p / 16, o = p % 16;
    float acc = 0.f;
    for (int j = 0; j < 64; ++j) acc += x1[n * 64 + j] * W2[j * 16 + o];
    h2[p] = acc;
  }
  __syncthreads();
  for (int n = tid; n < NSUP; n += 256) {
    float a = 0.f, d2 = 0.f;
    for (int o = 0; o < 16; ++o) {
      float hv = h2[n * 16 + o];
      a += hv * as2[o];
      d2 += hv * ad2[o];
    }
    es2[n] = a; ed2[n] = d2;
  }
  __syncthreads();
  for (int p = tid; p < NSUP * 16; p += 256) {
    int n = p / 16, o = p % 16;
    int rr = n % RR;
    float ov;
    if (rr == 0) ov = h2[p];
    else {
      int hub = n - rr;
      float eh = es2[hub] + ed2[n];
      float esf = es2[n] + ed2[n];
      eh = eh > 0.f ? eh : 0.2f * eh;
      esf = esf > 0.f ? esf : 0.2f * esf;
      float m = fmaxf(eh, esf);
      float wh = expf(eh - m), ws2 = expf(esf - m);
      ov = (wh * h2[hub * 16 + o] + ws2 * h2[p]) / (wh + ws2);
    }
    float v = ov + b2[o];
    x2[p] = v > 0.f ? v : expm1f(v);
  }
  __syncthreads();
  if (tid < BB) {
    double m = 0.0, v2 = 0.0;
    for (int q = 0; q < RR * 16; ++q) {
      float val = x2[tid * RR * 16 + q];
      m += val; v2 += (double)val * val;
    }
    m /= (RR * 16.0); v2 = v2 / (RR * 16.0) - m * m;
    stat[tid] = (float)m;
    stat[8 + tid] = (float)(1.0 / sqrt(v2 + 1e-5));
  }
  __syncthreads();
  for (int p = tid; p < NSUP * 16; p += 256) {
    int n = p / 16, o = p % 16, bb = n / RR;
    x2[p] = (x2[p] - stat[bb]) * stat[8 + bb] * lnw2[o] + lnb2[o];
  }
  __syncthreads();
  if (tid < BB * 2) {
    int bb = tid / 2, t = tid % 2;
    float acc = linb[t];
    for (int o = 0; o < 16; ++o) {
      float pm = 0.f;
      for (int rr = 0; rr < RR; ++rr) pm += x2[(bb * RR + rr) * 16 + o];
      pm /= (float)RR;
      acc += pm * linw[o * 2 + t];
    }
    out[bb * 2 + t] = acc;
  }
}

extern "C" void kernel_launch(void* const* d_in, const int* in_sizes, int n_in,
                              void* d_out, int out_size, void* d_ws, size_t ws_size,
                              hipStream_t stream) {
  const float* roi_x = (const float*)d_in[0];
  const int* ei = (const int*)d_in[1];
  const float* cen = (const float*)d_in[2];
  const float* gcn_w = (const float*)d_in[3];
  const float* gcn_b = (const float*)d_in[4];
  const float* ln_w = (const float*)d_in[5];
  const float* ln_b = (const float*)d_in[6];
  const float* topk_w = (const float*)d_in[7];
  const float* gat1_w = (const float*)d_in[8];
  const float* as1 = (const float*)d_in[9];
  const float* ad1 = (const float*)d_in[10];
  const float* b1 = (const float*)d_in[11];
  const float* lnw1 = (const float*)d_in[12];
  const float* lnb1 = (const float*)d_in[13];
  const float* W2 = (const float*)d_in[14];
  const float* as2 = (const float*)d_in[15];
  const float* ad2 = (const float*)d_in[16];
  const float* b2 = (const float*)d_in[17];
  const float* lnw2 = (const float*)d_in[18];
  const float* lnb2 = (const float*)d_in[19];
  const float* linw = (const float*)d_in[20];
  const float* linb = (const float*)d_in[21];
  float* out = (float*)d_out;

  // ws (bytes): v4g f32[80*8192*4]=10.49MB | zg f32[80*8192*4]=10.49MB | tg f32[80*8192]=2.62MB
  //  | partsS f64[640]=5KB | partsC f32[2560]=10KB | qo8 u16[80*8192]=1.31MB | et8 i32[640]
  //  | feats f32[1520] | rank u8[80*EPB]=10.49MB   total ~35.4MB (<=44.57MB proven)
  char* wsb = (char*)d_ws;
  float* v4g = (float*)wsb;
  float* zg = (float*)(wsb + (size_t)80 * NN * 4 * 4);
  float* tg = (float*)((char*)zg + (size_t)80 * NN * 4 * 4);
  double* partsS = (double*)((char*)tg + (size_t)80 * NN * 4);
  float* partsC = (float*)((char*)partsS + 640 * 8);
  unsigned short* qo8 = (unsigned short*)((char*)partsC + 2560 * 4);
  int* et8 = (int*)((char*)qo8 + (size_t)80 * 8192 * 2);
  float* feats = (float*)((char*)et8 + 640 * 4);
  unsigned char* rankg = (unsigned char*)((char*)feats + (size_t)RR * BB * 19 * 4);

  count_kernel<<<640, 1024, 0, stream>>>(ei, roi_x, rankg, qo8, et8, zg);
  scatfuse_kernel<<<320, 1024, 0, stream>>>(ei, zg, rankg, qo8, et8,
                                            gcn_w, gcn_b, ln_w, topk_w,
                                            v4g, tg, partsS, partsC);
  roiB_kernel<<<80, 1024, 0, stream>>>(tg, v4g, partsS, partsC,
                                       gcn_w, gcn_b, ln_w, ln_b, topk_w, cen, feats);
  super_kernel<<<1, 256, 0, stream>>>(feats, gat1_w, as1, ad1, b1, lnw1, lnb1,
                                      W2, as2, ad2, b2, lnw2, lnb2, linw, linb, out);
}

// Round 23
// 217.797 us; speedup vs baseline: 1.0163x; 1.0163x over previous
//
#include <hip/hip_runtime.h>
#include <hip/hip_bf16.h>
#include <math.h>

// Problem constants (match reference)
#define RR 10
#define BB 8
#define NN 8192
#define HH 8
#define BN 65536            // BB*NN nodes per ROI
#define EE (1u << 20)       // directed edges per ROI = 2*B*EPAIR
#define EPB (EE / BB)       // 131072 directed edges per (ROI,patient), contiguous
#define NPAIR (EPB / 2)     // 65536 undirected pairs per (r,b)
#define KK 4096             // TopKPooling keeps K of NN
#define NSUP 80             // B*R super nodes
#define CSRL8 17408         // LDS CSR slots per EIGHTH: mean 16384, sigma~120 -> +8.5 sigma

#define NTL(p) __builtin_nontemporal_load(p)
typedef int vi4 __attribute__((ext_vector_type(4)));   // clang vector: valid for nontemporal builtin

// ---------------- k1: per-(rb, node-EIGHTH) in-degree count + rank (uchar) + z = x*dis ----------------
// UNCHANGED from R22 (count is at the LDS-atomic throughput floor; repartitioning can't help).
__global__ __launch_bounds__(1024)
void count_kernel(const int* __restrict__ ei, const float* __restrict__ x,
                  unsigned char* __restrict__ rankg,
                  unsigned short* __restrict__ qo8g, int* __restrict__ et8g,
                  float* __restrict__ zg) {
  const int bid = blockIdx.x;
  const int rb = bid % 80;
  const int p = bid / 80;                 // node eighth 0..7
  const int r = rb / BB;
  const int b = rb % BB;
  const int tid = threadIdx.x;

  __shared__ int scnt[1024];
  __shared__ int ps[1024];
  scnt[tid] = 0;
  __syncthreads();

  const int* up = ei + (size_t)r * 2u * EE + (size_t)b * EPB;        // pair u side
  const int* vp = ei + (size_t)r * 2u * EE + EE + (size_t)b * EPB;   // pair v side
  unsigned char* rk = rankg + (size_t)rb * EPB;

#define CNT(U, V, E)                                                \
  {                                                                 \
    int lv = (V) & (NN - 1);                                        \
    if ((lv >> 10) == p) {                                          \
      int t0 = atomicAdd(&scnt[lv & 1023], 1);                      \
      rk[E] = (unsigned char)t0;                                    \
    }                                                               \
    int lu = (U) & (NN - 1);                                        \
    if ((lu >> 10) == p) {                                          \
      int t1 = atomicAdd(&scnt[lu & 1023], 1);                      \
      rk[(E) + NPAIR] = (unsigned char)t1;                          \
    }                                                               \
  }
#pragma unroll 4
  for (int it = 0; it < 16; ++it) {
    int e = it * 4096 + tid * 4;
    vi4 uu = NTL((const vi4*)(up + e));
    vi4 vv = NTL((const vi4*)(vp + e));
    CNT(uu.x, vv.x, e) CNT(uu.y, vv.y, e + 1)
    CNT(uu.z, vv.z, e + 2) CNT(uu.w, vv.w, e + 3)
  }
#undef CNT
  __syncthreads();

  // inclusive scan over this eighth's 1024 counts (1 element/thread)
  int a = scnt[tid];
  ps[tid] = a;
  __syncthreads();
  for (int s2 = 1; s2 < 1024; s2 <<= 1) {
    int v = 0;
    if (tid >= s2) v = ps[tid - s2];
    __syncthreads();
    ps[tid] += v;
    __syncthreads();
  }
  int incl = ps[tid];
  qo8g[(size_t)rb * 8192 + (size_t)p * 1024 + tid] = (unsigned short)(incl - a);
  if (tid == 1023) et8g[rb * 8 + p] = incl;

  // z tail: z[n] = x[n] * rsqrt(deg+1)
  {
    int n = p * 1024 + tid;
    const float4* x4 = (const float4*)x + (size_t)r * BN + (size_t)b * NN;
    float4* z4 = (float4*)zg + (size_t)rb * NN;
    float ds = rsqrtf((float)a + 1.0f);
    float4 xv = x4[n];
    z4[n] = make_float4(xv.x * ds, xv.y * ds, xv.z * ds, xv.w * ds);
  }
}

// ---------------- k2: per-(rb, node-EIGHTH) LDS-CSR scatter + z-pull + fused GCN epilogue ----------------
// 512 threads, 39KB LDS -> 4 blocks/CU, grid 640 all-resident (uniform 2-3 blocks/CU).
// R22 PMC: quarter/1024thr left 192 CUs at 16 waves (straggler 1.6x). Eighth offsets load
// directly from count's qo8 (no reconstruction).
__global__ __launch_bounds__(512)
void scatfuse_kernel(const int* __restrict__ ei, const float* __restrict__ zg,
                     const unsigned char* __restrict__ rankg,
                     const unsigned short* __restrict__ qo8g, const int* __restrict__ et8g,
                     const float* __restrict__ gcn_w, const float* __restrict__ gcn_b,
                     const float* __restrict__ ln_w, const float* __restrict__ topk_w,
                     float* __restrict__ v4g, float* __restrict__ tg,
                     double* __restrict__ partsS, float* __restrict__ partsC) {
  const int bid = blockIdx.x;
  const int rb = bid % 80;
  const int e8 = bid / 80;                 // node eighth 0..7
  const int r = rb / BB;
  const int b = rb % BB;
  const int tid = threadIdx.x;

  __shared__ unsigned short qoE[1025];                 // eighth-local offsets (+sentinel)
  __shared__ __align__(16) unsigned short csrL[CSRL8]; // 34.8 KB -> ~39KB total, 4 blk/CU

  const unsigned short* qo8 = qo8g + (size_t)rb * 8192 + (size_t)e8 * 1024;
  for (int i = tid; i < 1024; i += 512) qoE[i] = qo8[i];
  if (tid == 0) qoE[1024] = (unsigned short)et8g[rb * 8 + e8];
  __syncthreads();

  const int* up = ei + (size_t)r * 2u * EE + (size_t)b * EPB;
  const int* vp = ei + (size_t)r * 2u * EE + EE + (size_t)b * EPB;
  const unsigned char* rk = rankg + (size_t)rb * EPB;

#define SCAT(U, V, RA, RB2)                                         \
  {                                                                 \
    int lv = (V) & (NN - 1);                                        \
    if ((lv >> 10) == e8) {                                         \
      csrL[(int)qoE[lv & 1023] + (int)(RA)] =                       \
          (unsigned short)((U) & (NN - 1));                         \
    }                                                               \
    int lu = (U) & (NN - 1);                                        \
    if ((lu >> 10) == e8) {                                         \
      csrL[(int)qoE[lu & 1023] + (int)(RB2)] =                      \
          (unsigned short)((V) & (NN - 1));                         \
    }                                                               \
  }
#pragma unroll 4
  for (int it = 0; it < 32; ++it) {
    int e = it * 2048 + tid * 4;
    unsigned ra = NTL((const unsigned*)(rk + e));           // ranks dirs u->v, edges e..e+3
    unsigned rbv = NTL((const unsigned*)(rk + NPAIR + e));  // ranks dirs v->u
    vi4 uu = NTL((const vi4*)(up + e));
    vi4 vv = NTL((const vi4*)(vp + e));
    SCAT(uu.x, vv.x, ra & 255u, rbv & 255u)
    SCAT(uu.y, vv.y, (ra >> 8) & 255u, (rbv >> 8) & 255u)
    SCAT(uu.z, vv.z, (ra >> 16) & 255u, (rbv >> 16) & 255u)
    SCAT(uu.w, vv.w, (ra >> 24) & 255u, (rbv >> 24) & 255u)
  }
#undef SCAT
  __syncthreads();

  // per-r constants (wave-uniform -> scalar loads)
  const float* wp = gcn_w + r * 32;
  const float* bgp = gcn_b + r * 8;
  float lwwt[8];
#pragma unroll
  for (int c = 0; c < 8; ++c) lwwt[c] = ln_w[r * 8 + c] * topk_w[r * 8 + c];

  const float4* z4 = (const float4*)zg + (size_t)rb * NN;
  float4* v4o = (float4*)v4g + (size_t)rb * NN;
  float* trow = tg + (size_t)rb * NN;

  double s1 = 0.0, s2 = 0.0;
  float ch[8] = {0, 0, 0, 0, 0, 0, 0, 0};

#pragma unroll
  for (int k = 0; k < 2; ++k) {
    int idx = tid + k * 512;              // index within eighth
    int n = e8 * 1024 + idx;              // local node id
    int o = (int)qoE[idx];
    int c = (int)qoE[idx + 1] - o;
    float4 zn = z4[n];                    // own z (coalesced)
    float sx = zn.x, sy = zn.y, sz = zn.z, sw = zn.w;   // self-term seed
    int j = 0;
    for (; j + 3 < c; j += 4) {
      int n0 = csrL[o + j], n1 = csrL[o + j + 1], n2 = csrL[o + j + 2], n3 = csrL[o + j + 3];
      float4 a0 = z4[n0], a1 = z4[n1], a2 = z4[n2], a3 = z4[n3];
      sx += a0.x + a1.x + a2.x + a3.x;
      sy += a0.y + a1.y + a2.y + a3.y;
      sz += a0.z + a1.z + a2.z + a3.z;
      sw += a0.w + a1.w + a2.w + a3.w;
    }
    for (; j < c; ++j) {
      int n0 = csrL[o + j];
      float4 a0 = z4[n0];
      sx += a0.x; sy += a0.y; sz += a0.z; sw += a0.w;
    }
    float dd = rsqrtf((float)c + 1.0f);
    float v0 = sx * dd, v1 = sy * dd, v2 = sz * dd, v3 = sw * dd;
    v4o[n] = make_float4(v0, v1, v2, v3);
    float t = 0.f;
#pragma unroll
    for (int cc = 0; cc < 8; ++cc) {
      float h = fmaxf(v0 * wp[cc] + v1 * wp[8 + cc] + v2 * wp[16 + cc] + v3 * wp[24 + cc] + bgp[cc], 0.0f);
      s1 += h;
      s2 += (double)h * h;
      ch[cc] += h;
      t += h * lwwt[cc];
    }
    trow[n] = t;
  }

  // block-reduce partials (8 waves); reuse csrL as scratch (done with CSR)
  __syncthreads();
  double* wredS = (double*)csrL;              // 8 x 2 doubles @ 0
  float* wredC = (float*)(csrL + 512);        // 8 x 8 floats @ +1024B
  int lane = tid & 63, wid = tid >> 6;
#pragma unroll
  for (int off = 32; off > 0; off >>= 1) {
    s1 += __shfl_down(s1, off);
    s2 += __shfl_down(s2, off);
#pragma unroll
    for (int cc = 0; cc < 8; ++cc) ch[cc] += __shfl_down(ch[cc], off);
  }
  if (lane == 0) {
    wredS[wid * 2] = s1;
    wredS[wid * 2 + 1] = s2;
#pragma unroll
    for (int cc = 0; cc < 8; ++cc) wredC[wid * 8 + cc] = ch[cc];
  }
  __syncthreads();
  if (tid == 0) {
    double a = 0.0, b3 = 0.0;
    for (int w2 = 0; w2 < 8; ++w2) { a += wredS[w2 * 2]; b3 += wredS[w2 * 2 + 1]; }
    partsS[bid * 2] = a;
    partsS[bid * 2 + 1] = b3;
  }
  if (tid < 8) {
    float sc = 0.f;
    for (int w2 = 0; w2 < 8; ++w2) sc += wredC[w2 * 8 + tid];
    partsC[bid * 8 + tid] = sc;
  }
}

// ---------------- k3: per-(r,b) stats combine + score + WAVE-PARALLEL radix-select + pools ----------------
__global__ __launch_bounds__(1024)
void roiB_kernel(const float* __restrict__ tg, const float* __restrict__ v4g,
                 const double* __restrict__ partsS, const float* __restrict__ partsC,
                 const float* __restrict__ gcn_w, const float* __restrict__ gcn_b,
                 const float* __restrict__ ln_w, const float* __restrict__ ln_b,
                 const float* __restrict__ topk_w, const float* __restrict__ cen,
                 float* __restrict__ feats) {
  const int rb = blockIdx.x;
  const int r = rb / BB;
  const int tid = threadIdx.x;
  const int lane = tid & 63, wid = tid >> 6;

  __shared__ int histW[16 * 256];     // wave-private histograms (16 KB)
  __shared__ int wtot[16];
  __shared__ float chS[8];
  __shared__ float fvSum[8];
  __shared__ int cntGt;
  __shared__ int selb, kleft;
  __shared__ float sstat[2];

  float lw[8], lb[8], wt[8], w[32], bg[8];
  float wn2 = 0.f, L1 = 0.f, B1 = 0.f;
#pragma unroll
  for (int i = 0; i < 32; ++i) w[i] = gcn_w[r * 32 + i];
#pragma unroll
  for (int c = 0; c < 8; ++c) {
    lw[c] = ln_w[r * 8 + c];
    lb[c] = ln_b[r * 8 + c];
    wt[c] = topk_w[r * 8 + c];
    bg[c] = gcn_b[r * 8 + c];
    wn2 += wt[c] * wt[c];
    L1 += lw[c] * wt[c];
    B1 += lb[c] * wt[c];
  }
  const float invn = 1.0f / sqrtf(wn2);

  if (tid == 0) {
    double s1 = 0.0, s2 = 0.0;
    for (int p = 0; p < 8; ++p) {
      s1 += partsS[(p * 80 + rb) * 2];
      s2 += partsS[(p * 80 + rb) * 2 + 1];
    }
    const double M = (double)NN * HH;
    double mu = s1 / M;
    double var = s2 / M - mu * mu;
    sstat[0] = (float)mu;
    sstat[1] = (float)(1.0 / sqrt(var + 1e-5));
    cntGt = 0;
  }
  if (tid < 8) {
    float sc = 0.f;
    for (int p = 0; p < 8; ++p) sc += partsC[(p * 80 + rb) * 8 + tid];
    chS[tid] = sc;
    fvSum[tid] = 0.f;
  }
  __syncthreads();
  const float muf = sstat[0];
  const float rstd = sstat[1];
  const float C0 = B1 - rstd * muf * L1;   // pre = rstd*t + C0

  const float* trow = tg + (size_t)rb * NN;
  float sv[8];
  unsigned fl[8];
#pragma unroll
  for (int i = 0; i < 8; ++i) {
    int n = tid * 8 + i;
    float s = tanhf((rstd * trow[n] + C0) * invn);
    sv[i] = s;
    unsigned u = __float_as_uint(s);
    fl[i] = (u & 0x80000000u) ? ~u : (u | 0x80000000u);  // monotonic flip
  }

  // Radix-select K-th largest (exact), 4 passes of 8 bits.
  unsigned prefix = 0;
  int kneed = KK;
  for (int shift = 24; shift >= 0; shift -= 8) {
#pragma unroll
    for (int z = 0; z < 4; ++z) histW[tid + z * 1024] = 0;
    __syncthreads();
#pragma unroll
    for (int i = 0; i < 8; ++i) {
      bool m = (shift == 24) || ((fl[i] >> (shift + 8)) == prefix);
      if (m) atomicAdd(&histW[wid * 256 + ((fl[i] >> shift) & 255)], 1);
    }
    __syncthreads();
    if (wid == 0) {
      // lane owns bins [4*lane .. 4*lane+3]; combine 16 wave-hists
      int b0 = lane * 4;
      int t0 = 0, t1 = 0, t2 = 0, t3 = 0;
      for (int w2 = 0; w2 < 16; ++w2) {
        const int* hp2 = &histW[w2 * 256 + b0];
        t0 += hp2[0]; t1 += hp2[1]; t2 += hp2[2]; t3 += hp2[3];
      }
      int s3 = t3, s2i = t2 + s3, s1i = t1 + s2i, s0 = t0 + s1i;  // in-lane suffix
      int v = s0;
#pragma unroll
      for (int off = 1; off < 64; off <<= 1) {
        int o = __shfl_down(v, off);
        v += (lane + off < 64) ? o : 0;           // v = sum over lanes >= lane
      }
      int above = v - s0;                          // = S[b0+4] (sum over bins >= b0+4)
      int S3 = above + s3, S2 = above + s2i, S1 = above + s1i, S0 = above + s0;
      // unique crossing bin: S[b] >= kneed > S[b+1]
      if (S3 >= kneed && above < kneed)      { selb = b0 + 3; kleft = kneed - above; }
      else if (S2 >= kneed && S3 < kneed)    { selb = b0 + 2; kleft = kneed - S3; }
      else if (S1 >= kneed && S2 < kneed)    { selb = b0 + 1; kleft = kneed - S2; }
      else if (S0 >= kneed && S1 < kneed)    { selb = b0;     kleft = kneed - S1; }
    }
    __syncthreads();
    prefix = (prefix << 8) | (unsigned)selb;
    kneed = kleft;
  }
  float tau = (prefix & 0x80000000u) ? __uint_as_float(prefix & 0x7fffffffu)
                                     : __uint_as_float(~prefix);

  // tie-break lowest-index-first: 2-level scan (wave shfl + 16 wave totals)
  int cg = 0, ct = 0;
#pragma unroll
  for (int i = 0; i < 8; ++i) {
    if (sv[i] > tau) cg++;
    else if (sv[i] == tau) ct++;
  }
  int wcg = cg;
#pragma unroll
  for (int off = 32; off > 0; off >>= 1) wcg += __shfl_down(wcg, off);
  if (lane == 0) atomicAdd(&cntGt, wcg);
  int sc = ct;
#pragma unroll
  for (int off = 1; off < 64; off <<= 1) {
    int o = __shfl_up(sc, off);
    if (lane >= off) sc += o;                      // inclusive scan within wave
  }
  if (lane == 63) wtot[wid] = sc;
  __syncthreads();
  int wbase = 0;
  for (int w2 = 0; w2 < wid; ++w2) wbase += wtot[w2];
  int rank = wbase + sc - ct;                      // exclusive tie-rank in block
  int quota = KK - cntGt;

  const float4* v4r = (const float4*)v4g + (size_t)rb * NN;
  float fva[8] = {0, 0, 0, 0, 0, 0, 0, 0};
#pragma unroll
  for (int i = 0; i < 8; ++i) {
    bool inc = sv[i] > tau;
    if (!inc && sv[i] == tau) { inc = (rank < quota); rank++; }
    if (inc) {
      int n = tid * 8 + i;
      float4 vv = v4r[n];
#pragma unroll
      for (int c = 0; c < 8; ++c) {
        float h = fmaxf(vv.x * w[c] + vv.y * w[8 + c] + vv.z * w[16 + c] + vv.w * w[24 + c] + bg[c], 0.0f);
        float hn = (h - muf) * rstd * lw[c] + lb[c];
        fva[c] += hn * sv[i];
      }
    }
  }
#pragma unroll
  for (int c = 0; c < 8; ++c) atomicAdd(&fvSum[c], fva[c]);
  __syncthreads();

  size_t fo = (size_t)rb * 19;
  if (tid < 8) {
    feats[fo + tid] = ((chS[tid] - (float)NN * muf) * rstd * lw[tid]) / (float)NN + lb[tid];
    feats[fo + 8 + tid] = fvSum[tid] / (float)KK;
  }
  if (tid >= 16 && tid < 19) {
    feats[fo + tid] = cen[(size_t)rb * 3 + (tid - 16)];
  }
}

// ---------------- super graph: GAT1 -> LN -> GAT2 -> LN -> pool -> linear ----------------
__global__ __launch_bounds__(256)
void super_kernel(const float* __restrict__ feats,
                  const float* __restrict__ W1, const float* __restrict__ as1,
                  const float* __restrict__ ad1, const float* __restrict__ b1,
                  const float* __restrict__ lnw1, const float* __restrict__ lnb1,
                  const float* __restrict__ W2, const float* __restrict__ as2,
                  const float* __restrict__ ad2, const float* __restrict__ b2,
                  const float* __restrict__ lnw2, const float* __restrict__ lnb2,
                  const float* __restrict__ linw, const float* __restrict__ linb,
                  float* __restrict__ out) {
  __shared__ float sx[NSUP * 19];
  __shared__ float h1[NSUP * 64];
  __shared__ float x1[NSUP * 64];
  __shared__ float es1[NSUP * 4], ed1[NSUP * 4];
  __shared__ float h2[NSUP * 16], x2[NSUP * 16];
  __shared__ float es2[NSUP], ed2[NSUP];
  __shared__ float stat[16];
  const int tid = threadIdx.x;

  for (int i = tid; i < NSUP * 19; i += 256) {
    int n = i / 19, c = i % 19;
    int bb = n / RR, rr = n % RR;
    sx[i] = feats[(size_t)(rr * BB + bb) * 19 + c];
  }
  __syncthreads();
  for (int p = tid; p < NSUP * 64; p += 256) {
    int n = p / 64, j = p % 64;
    float acc = 0.f;
    for (int k2 = 0; k2 < 19; ++k2) acc += sx[n * 19 + k2] * W1[k2 * 64 + j];
    h1[p] = acc;
  }
  __syncthreads();
  for (int p = tid; p < NSUP * 4; p += 256) {
    int n = p / 4, hd = p % 4;
    float a = 0.f, d2 = 0.f;
    for (int o = 0; o < 16; ++o) {
      float hv = h1[n * 64 + hd * 16 + o];
      a += hv * as1[hd * 16 + o];
      d2 += hv * ad1[hd * 16 + o];
    }
    es1[p] = a; ed1[p] = d2;
  }
  __syncthreads();
  for (int p = tid; p < NSUP * 64; p += 256) {
    int n = p / 64, j = p % 64, hd = j / 16;
    int rr = n % RR;
    float o;
    if (rr == 0) {
      o = h1[p];
    } else {
      int hub = n - rr;
      float eh = es1[hub * 4 + hd] + ed1[n * 4 + hd];
      float esf = es1[n * 4 + hd] + ed1[n * 4 + hd];
      eh = eh > 0.f ? eh : 0.2f * eh;
      esf = esf > 0.f ? esf : 0.2f * esf;
      float m = fmaxf(eh, esf);
      float wh = expf(eh - m), ws2 = expf(esf - m);
      o = (wh * h1[hub * 64 + j] + ws2 * h1[n * 64 + j]) / (wh + ws2);
    }
    float v = o + b1[j];
    x1[p] = v > 0.f ? v : expm1f(v);   // elu
  }
  __syncthreads();
  if (tid < BB) {
    double m = 0.0, v2 = 0.0;
    for (int q = 0; q < RR * 64; ++q) {
      float val = x1[tid * RR * 64 + q];
      m += val; v2 += (double)val * val;
    }
    m /= (RR * 64.0); v2 = v2 / (RR * 64.0) - m * m;
    stat[tid] = (float)m;
    stat[8 + tid] = (float)(1.0 / sqrt(v2 + 1e-5));
  }
  __syncthreads();
  for (int p = tid; p < NSUP * 64; p += 256) {
    int n = p / 64, j = p % 64, bb = n / RR;
    x1[p] = (x1[p] - stat[bb]) * stat[8 + bb] * lnw1[j] + lnb1[j];
  }
  __syncthreads();
  for (int p = tid; p < NSUP * 16; p += 256) {
    int n = p / 16, o = p % 16;
    float acc = 0.f;
    for (int j = 0; j < 64; ++j) acc += x1[n * 64 + j] * W2[j * 16 + o];
    h2[p] = acc;
  }
  __syncthreads();
  for (int n = tid; n < NSUP; n += 256) {
    float a = 0.f, d2 = 0.f;
    for (int o = 0; o < 16; ++o) {
      float hv = h2[n * 16 + o];
      a += hv * as2[o];
      d2 += hv * ad2[o];
    }
    es2[n] = a; ed2[n] = d2;
  }
  __syncthreads();
  for (int p = tid; p < NSUP * 16; p += 256) {
    int n = p / 16, o = p % 16;
    int rr = n % RR;
    float ov;
    if (rr == 0) ov = h2[p];
    else {
      int hub = n - rr;
      float eh = es2[hub] + ed2[n];
      float esf = es2[n] + ed2[n];
      eh = eh > 0.f ? eh : 0.2f * eh;
      esf = esf > 0.f ? esf : 0.2f * esf;
      float m = fmaxf(eh, esf);
      float wh = expf(eh - m), ws2 = expf(esf - m);
      ov = (wh * h2[hub * 16 + o] + ws2 * h2[p]) / (wh + ws2);
    }
    float v = ov + b2[o];
    x2[p] = v > 0.f ? v : expm1f(v);
  }
  __syncthreads();
  if (tid < BB) {
    double m = 0.0, v2 = 0.0;
    for (int q = 0; q < RR * 16; ++q) {
      float val = x2[tid * RR * 16 + q];
      m += val; v2 += (double)val * val;
    }
    m /= (RR * 16.0); v2 = v2 / (RR * 16.0) - m * m;
    stat[tid] = (float)m;
    stat[8 + tid] = (float)(1.0 / sqrt(v2 + 1e-5));
  }
  __syncthreads();
  for (int p = tid; p < NSUP * 16; p += 256) {
    int n = p / 16, o = p % 16, bb = n / RR;
    x2[p] = (x2[p] - stat[bb]) * stat[8 + bb] * lnw2[o] + lnb2[o];
  }
  __syncthreads();
  if (tid < BB * 2) {
    int bb = tid / 2, t = tid % 2;
    float acc = linb[t];
    for (int o = 0; o < 16; ++o) {
      float pm = 0.f;
      for (int rr = 0; rr < RR; ++rr) pm += x2[(bb * RR + rr) * 16 + o];
      pm /= (float)RR;
      acc += pm * linw[o * 2 + t];
    }
    out[bb * 2 + t] = acc;
  }
}

extern "C" void kernel_launch(void* const* d_in, const int* in_sizes, int n_in,
                              void* d_out, int out_size, void* d_ws, size_t ws_size,
                              hipStream_t stream) {
  const float* roi_x = (const float*)d_in[0];
  const int* ei = (const int*)d_in[1];
  const float* cen = (const float*)d_in[2];
  const float* gcn_w = (const float*)d_in[3];
  const float* gcn_b = (const float*)d_in[4];
  const float* ln_w = (const float*)d_in[5];
  const float* ln_b = (const float*)d_in[6];
  const float* topk_w = (const float*)d_in[7];
  const float* gat1_w = (const float*)d_in[8];
  const float* as1 = (const float*)d_in[9];
  const float* ad1 = (const float*)d_in[10];
  const float* b1 = (const float*)d_in[11];
  const float* lnw1 = (const float*)d_in[12];
  const float* lnb1 = (const float*)d_in[13];
  const float* W2 = (const float*)d_in[14];
  const float* as2 = (const float*)d_in[15];
  const float* ad2 = (const float*)d_in[16];
  const float* b2 = (const float*)d_in[17];
  const float* lnw2 = (const float*)d_in[18];
  const float* lnb2 = (const float*)d_in[19];
  const float* linw = (const float*)d_in[20];
  const float* linb = (const float*)d_in[21];
  float* out = (float*)d_out;

  // ws (bytes): v4g f32[80*8192*4]=10.49MB | zg f32[80*8192*4]=10.49MB | tg f32[80*8192]=2.62MB
  //  | partsS f64[1280]=10KB | partsC f32[5120]=20KB | qo8 u16[80*8192]=1.31MB | et8 i32[640]
  //  | feats f32[1520] | rank u8[80*EPB]=10.49MB   total ~35.4MB (<=44.57MB proven)
  char* wsb = (char*)d_ws;
  float* v4g = (float*)wsb;
  float* zg = (float*)(wsb + (size_t)80 * NN * 4 * 4);
  float* tg = (float*)((char*)zg + (size_t)80 * NN * 4 * 4);
  double* partsS = (double*)((char*)tg + (size_t)80 * NN * 4);
  float* partsC = (float*)((char*)partsS + 1280 * 8);
  unsigned short* qo8 = (unsigned short*)((char*)partsC + 5120 * 4);
  int* et8 = (int*)((char*)qo8 + (size_t)80 * 8192 * 2);
  float* feats = (float*)((char*)et8 + 640 * 4);
  unsigned char* rankg = (unsigned char*)((char*)feats + (size_t)RR * BB * 19 * 4);

  count_kernel<<<640, 1024, 0, stream>>>(ei, roi_x, rankg, qo8, et8, zg);
  scatfuse_kernel<<<640, 512, 0, stream>>>(ei, zg, rankg, qo8, et8,
                                           gcn_w, gcn_b, ln_w, topk_w,
                                           v4g, tg, partsS, partsC);
  roiB_kernel<<<80, 1024, 0, stream>>>(tg, v4g, partsS, partsC,
                                       gcn_w, gcn_b, ln_w, ln_b, topk_w, cen, feats);
  super_kernel<<<1, 256, 0, stream>>>(feats, gat1_w, as1, ad1, b1, lnw1, lnb1,
                                      W2, as2, ad2, b2, lnw2, lnb2, linw, linb, out);
}

// Round 24
// 179.812 us; speedup vs baseline: 1.2310x; 1.2112x over previous
//
#include <hip/hip_runtime.h>
#include <hip/hip_bf16.h>
#include <math.h>

// Problem constants (match reference)
#define RR 10
#define BB 8
#define NN 8192
#define HH 8
#define BN 65536            // BB*NN nodes per ROI
#define EE (1u << 20)       // directed edges per ROI = 2*B*EPAIR
#define EPB (EE / BB)       // 131072 directed edges per (ROI,patient), contiguous
#define NPAIR (EPB / 2)     // 65536 undirected pairs per (r,b)
#define KK 4096             // TopKPooling keeps K of NN
#define NSUP 80             // B*R super nodes
#define CSRL8 17408         // LDS CSR slots per EIGHTH: mean 16384, sigma~120 -> +8.5 sigma

#define NTL(p) __builtin_nontemporal_load(p)
typedef int vi4 __attribute__((ext_vector_type(4)));   // clang vector: valid for nontemporal builtin

// ---------------- k1: per-(rb, EDGE-CHUNK) count with FULL-LANE atomics ----------------
// Block owns 8192 pairs; full [8192] histogram in LDS -> every atomic is unconditional
// (64/64 lanes active vs 8/64 in the dst-partitioned scheme). Ranks are chunk-local (u8).
__global__ __launch_bounds__(1024)
void count_kernel(const int* __restrict__ ei, unsigned char* __restrict__ rankg,
                  unsigned char* __restrict__ Hg) {
  const int bid = blockIdx.x;
  const int rb = bid % 80;
  const int c = bid / 80;                 // edge chunk 0..7 (8192 pairs each)
  const int r = rb / BB;
  const int b = rb % BB;
  const int tid = threadIdx.x;

  __shared__ int hist[NN];                // 32 KB
  for (int i = tid; i < NN; i += 1024) hist[i] = 0;
  __syncthreads();

  const int* up = ei + (size_t)r * 2u * EE + (size_t)b * EPB;        // pair u side
  const int* vp = ei + (size_t)r * 2u * EE + EE + (size_t)b * EPB;   // pair v side
  unsigned char* rk = rankg + (size_t)rb * EPB;

#pragma unroll
  for (int it = 0; it < 2; ++it) {
    int e = c * 8192 + it * 4096 + tid * 4;
    vi4 uu = NTL((const vi4*)(up + e));
    vi4 vv = NTL((const vi4*)(vp + e));
#define DO(j, U, V)                                                 \
    {                                                               \
      int r0 = atomicAdd(&hist[(V) & (NN - 1)], 1);                 \
      rk[e + (j)] = (unsigned char)r0;                              \
      int r1 = atomicAdd(&hist[(U) & (NN - 1)], 1);                 \
      rk[e + (j) + NPAIR] = (unsigned char)r1;                      \
    }
    DO(0, uu.x, vv.x) DO(1, uu.y, vv.y) DO(2, uu.z, vv.z) DO(3, uu.w, vv.w)
#undef DO
  }
  __syncthreads();

  // persist chunk histogram (u8: per-chunk/dst count mean 2, max ~12)
  unsigned char* hg = Hg + ((size_t)rb * 8 + c) * NN;
  for (int i = tid; i < NN; i += 1024) hg[i] = (unsigned char)hist[i];
}

// ---------------- k1b: merge chunk histograms -> degree, qo8/et8, z = x*dis ----------------
__global__ __launch_bounds__(1024)
void merge_kernel(const unsigned char* __restrict__ Hg, const float* __restrict__ x,
                  unsigned short* __restrict__ qo8g, int* __restrict__ et8g,
                  float* __restrict__ zg) {
  const int bid = blockIdx.x;
  const int rb = bid % 80;
  const int p = bid / 80;                 // node eighth 0..7
  const int r = rb / BB;
  const int b = rb % BB;
  const int tid = threadIdx.x;

  __shared__ int ps[1024];
  int n = p * 1024 + tid;                 // thread owns one node
  const unsigned char* hg = Hg + (size_t)rb * 8 * NN;
  int deg = 0;
#pragma unroll
  for (int c = 0; c < 8; ++c) deg += (int)hg[(size_t)c * NN + n];

  ps[tid] = deg;
  __syncthreads();
  for (int s2 = 1; s2 < 1024; s2 <<= 1) {
    int v = 0;
    if (tid >= s2) v = ps[tid - s2];
    __syncthreads();
    ps[tid] += v;
    __syncthreads();
  }
  int incl = ps[tid];
  qo8g[(size_t)rb * 8192 + (size_t)p * 1024 + tid] = (unsigned short)(incl - deg);
  if (tid == 1023) et8g[rb * 8 + p] = incl;

  const float4* x4 = (const float4*)x + (size_t)r * BN + (size_t)b * NN;
  float4* z4 = (float4*)zg + (size_t)rb * NN;
  float ds = rsqrtf((float)deg + 1.0f);
  float4 xv = x4[n];
  z4[n] = make_float4(xv.x * ds, xv.y * ds, xv.z * ds, xv.w * ds);
}

// ---------------- k2: per-(rb, node-EIGHTH) LDS-CSR scatter (chunk-ordered) + z-pull + epilogue ----------------
// slot = qoCur[d] + chunk_rank; qoCur advances by Hg[c][d] after each chunk -> unique dense slots.
// Pull unchanged (uses original qoE). CSR content identical as a SET (list order irrelevant: we sum).
__global__ __launch_bounds__(512)
void scatfuse_kernel(const int* __restrict__ ei, const float* __restrict__ zg,
                     const unsigned char* __restrict__ rankg,
                     const unsigned short* __restrict__ qo8g, const int* __restrict__ et8g,
                     const unsigned char* __restrict__ Hg,
                     const float* __restrict__ gcn_w, const float* __restrict__ gcn_b,
                     const float* __restrict__ ln_w, const float* __restrict__ topk_w,
                     float* __restrict__ v4g, float* __restrict__ tg,
                     double* __restrict__ partsS, float* __restrict__ partsC) {
  const int bid = blockIdx.x;
  const int rb = bid % 80;
  const int e8 = bid / 80;                 // node eighth 0..7
  const int r = rb / BB;
  const int b = rb % BB;
  const int tid = threadIdx.x;

  __shared__ unsigned short qoE[1025];                 // eighth-local offsets (+sentinel), for pull
  __shared__ unsigned short qoCur[1024];               // running scatter offsets
  __shared__ __align__(16) unsigned short csrL[CSRL8]; // 34.8 KB -> ~39KB total, 4 blk/CU

  const unsigned short* qo8 = qo8g + (size_t)rb * 8192 + (size_t)e8 * 1024;
  for (int i = tid; i < 1024; i += 512) {
    unsigned short v = qo8[i];
    qoE[i] = v;
    qoCur[i] = v;
  }
  if (tid == 0) qoE[1024] = (unsigned short)et8g[rb * 8 + e8];
  __syncthreads();

  const int* up = ei + (size_t)r * 2u * EE + (size_t)b * EPB;
  const int* vp = ei + (size_t)r * 2u * EE + EE + (size_t)b * EPB;
  const unsigned char* rk = rankg + (size_t)rb * EPB;
  const unsigned char* hg = Hg + (size_t)rb * 8 * NN + (size_t)e8 * 1024;  // +c*NN per chunk

#define SCAT(U, V, RA, RB2)                                         \
  {                                                                 \
    int lv = (V) & (NN - 1);                                        \
    if ((lv >> 10) == e8) {                                         \
      csrL[(int)qoCur[lv & 1023] + (int)(RA)] =                     \
          (unsigned short)((U) & (NN - 1));                         \
    }                                                               \
    int lu = (U) & (NN - 1);                                        \
    if ((lu >> 10) == e8) {                                         \
      csrL[(int)qoCur[lu & 1023] + (int)(RB2)] =                    \
          (unsigned short)((V) & (NN - 1));                         \
    }                                                               \
  }
  for (int c = 0; c < 8; ++c) {
#pragma unroll
    for (int it = 0; it < 4; ++it) {
      int e = c * 8192 + it * 2048 + tid * 4;
      unsigned ra = NTL((const unsigned*)(rk + e));           // chunk-local ranks, dirs u->v
      unsigned rbv = NTL((const unsigned*)(rk + NPAIR + e));  // dirs v->u
      vi4 uu = NTL((const vi4*)(up + e));
      vi4 vv = NTL((const vi4*)(vp + e));
      SCAT(uu.x, vv.x, ra & 255u, rbv & 255u)
      SCAT(uu.y, vv.y, (ra >> 8) & 255u, (rbv >> 8) & 255u)
      SCAT(uu.z, vv.z, (ra >> 16) & 255u, (rbv >> 16) & 255u)
      SCAT(uu.w, vv.w, (ra >> 24) & 255u, (rbv >> 24) & 255u)
    }
    __syncthreads();
    for (int i = tid; i < 1024; i += 512)
      qoCur[i] = (unsigned short)((int)qoCur[i] + (int)hg[(size_t)c * NN + i]);
    __syncthreads();
  }
#undef SCAT

  // per-r constants (wave-uniform -> scalar loads)
  const float* wp = gcn_w + r * 32;
  const float* bgp = gcn_b + r * 8;
  float lwwt[8];
#pragma unroll
  for (int c = 0; c < 8; ++c) lwwt[c] = ln_w[r * 8 + c] * topk_w[r * 8 + c];

  const float4* z4 = (const float4*)zg + (size_t)rb * NN;
  float4* v4o = (float4*)v4g + (size_t)rb * NN;
  float* trow = tg + (size_t)rb * NN;

  double s1 = 0.0, s2 = 0.0;
  float ch[8] = {0, 0, 0, 0, 0, 0, 0, 0};

#pragma unroll
  for (int k = 0; k < 2; ++k) {
    int idx = tid + k * 512;              // index within eighth
    int n = e8 * 1024 + idx;              // local node id
    int o = (int)qoE[idx];
    int c = (int)qoE[idx + 1] - o;        // NOTE: qoE[1024] sentinel covers idx=1023
    float4 zn = z4[n];                    // own z (coalesced)
    float sx = zn.x, sy = zn.y, sz = zn.z, sw = zn.w;   // self-term seed
    int j = 0;
    for (; j + 3 < c; j += 4) {
      int n0 = csrL[o + j], n1 = csrL[o + j + 1], n2 = csrL[o + j + 2], n3 = csrL[o + j + 3];
      float4 a0 = z4[n0], a1 = z4[n1], a2 = z4[n2], a3 = z4[n3];
      sx += a0.x + a1.x + a2.x + a3.x;
      sy += a0.y + a1.y + a2.y + a3.y;
      sz += a0.z + a1.z + a2.z + a3.z;
      sw += a0.w + a1.w + a2.w + a3.w;
    }
    for (; j < c; ++j) {
      int n0 = csrL[o + j];
      float4 a0 = z4[n0];
      sx += a0.x; sy += a0.y; sz += a0.z; sw += a0.w;
    }
    float dd = rsqrtf((float)c + 1.0f);
    float v0 = sx * dd, v1 = sy * dd, v2 = sz * dd, v3 = sw * dd;
    v4o[n] = make_float4(v0, v1, v2, v3);
    float t = 0.f;
#pragma unroll
    for (int cc = 0; cc < 8; ++cc) {
      float h = fmaxf(v0 * wp[cc] + v1 * wp[8 + cc] + v2 * wp[16 + cc] + v3 * wp[24 + cc] + bgp[cc], 0.0f);
      s1 += h;
      s2 += (double)h * h;
      ch[cc] += h;
      t += h * lwwt[cc];
    }
    trow[n] = t;
  }

  // block-reduce partials (8 waves); reuse csrL as scratch (done with CSR)
  __syncthreads();
  double* wredS = (double*)csrL;              // 8 x 2 doubles @ 0
  float* wredC = (float*)(csrL + 512);        // 8 x 8 floats @ +1024B
  int lane = tid & 63, wid = tid >> 6;
#pragma unroll
  for (int off = 32; off > 0; off >>= 1) {
    s1 += __shfl_down(s1, off);
    s2 += __shfl_down(s2, off);
#pragma unroll
    for (int cc = 0; cc < 8; ++cc) ch[cc] += __shfl_down(ch[cc], off);
  }
  if (lane == 0) {
    wredS[wid * 2] = s1;
    wredS[wid * 2 + 1] = s2;
#pragma unroll
    for (int cc = 0; cc < 8; ++cc) wredC[wid * 8 + cc] = ch[cc];
  }
  __syncthreads();
  if (tid == 0) {
    double a = 0.0, b3 = 0.0;
    for (int w2 = 0; w2 < 8; ++w2) { a += wredS[w2 * 2]; b3 += wredS[w2 * 2 + 1]; }
    partsS[bid * 2] = a;
    partsS[bid * 2 + 1] = b3;
  }
  if (tid < 8) {
    float sc = 0.f;
    for (int w2 = 0; w2 < 8; ++w2) sc += wredC[w2 * 8 + tid];
    partsC[bid * 8 + tid] = sc;
  }
}

// ---------------- k3: per-(r,b) stats combine + score + WAVE-PARALLEL radix-select + pools ----------------
__global__ __launch_bounds__(1024)
void roiB_kernel(const float* __restrict__ tg, const float* __restrict__ v4g,
                 const double* __restrict__ partsS, const float* __restrict__ partsC,
                 const float* __restrict__ gcn_w, const float* __restrict__ gcn_b,
                 const float* __restrict__ ln_w, const float* __restrict__ ln_b,
                 const float* __restrict__ topk_w, const float* __restrict__ cen,
                 float* __restrict__ feats) {
  const int rb = blockIdx.x;
  const int r = rb / BB;
  const int tid = threadIdx.x;
  const int lane = tid & 63, wid = tid >> 6;

  __shared__ int histW[16 * 256];     // wave-private histograms (16 KB)
  __shared__ int wtot[16];
  __shared__ float chS[8];
  __shared__ float fvSum[8];
  __shared__ int cntGt;
  __shared__ int selb, kleft;
  __shared__ float sstat[2];

  float lw[8], lb[8], wt[8], w[32], bg[8];
  float wn2 = 0.f, L1 = 0.f, B1 = 0.f;
#pragma unroll
  for (int i = 0; i < 32; ++i) w[i] = gcn_w[r * 32 + i];
#pragma unroll
  for (int c = 0; c < 8; ++c) {
    lw[c] = ln_w[r * 8 + c];
    lb[c] = ln_b[r * 8 + c];
    wt[c] = topk_w[r * 8 + c];
    bg[c] = gcn_b[r * 8 + c];
    wn2 += wt[c] * wt[c];
    L1 += lw[c] * wt[c];
    B1 += lb[c] * wt[c];
  }
  const float invn = 1.0f / sqrtf(wn2);

  if (tid == 0) {
    double s1 = 0.0, s2 = 0.0;
    for (int p = 0; p < 8; ++p) {
      s1 += partsS[(p * 80 + rb) * 2];
      s2 += partsS[(p * 80 + rb) * 2 + 1];
    }
    const double M = (double)NN * HH;
    double mu = s1 / M;
    double var = s2 / M - mu * mu;
    sstat[0] = (float)mu;
    sstat[1] = (float)(1.0 / sqrt(var + 1e-5));
    cntGt = 0;
  }
  if (tid < 8) {
    float sc = 0.f;
    for (int p = 0; p < 8; ++p) sc += partsC[(p * 80 + rb) * 8 + tid];
    chS[tid] = sc;
    fvSum[tid] = 0.f;
  }
  __syncthreads();
  const float muf = sstat[0];
  const float rstd = sstat[1];
  const float C0 = B1 - rstd * muf * L1;   // pre = rstd*t + C0

  const float* trow = tg + (size_t)rb * NN;
  float sv[8];
  unsigned fl[8];
#pragma unroll
  for (int i = 0; i < 8; ++i) {
    int n = tid * 8 + i;
    float s = tanhf((rstd * trow[n] + C0) * invn);
    sv[i] = s;
    unsigned u = __float_as_uint(s);
    fl[i] = (u & 0x80000000u) ? ~u : (u | 0x80000000u);  // monotonic flip
  }

  // Radix-select K-th largest (exact), 4 passes of 8 bits.
  unsigned prefix = 0;
  int kneed = KK;
  for (int shift = 24; shift >= 0; shift -= 8) {
#pragma unroll
    for (int z = 0; z < 4; ++z) histW[tid + z * 1024] = 0;
    __syncthreads();
#pragma unroll
    for (int i = 0; i < 8; ++i) {
      bool m = (shift == 24) || ((fl[i] >> (shift + 8)) == prefix);
      if (m) atomicAdd(&histW[wid * 256 + ((fl[i] >> shift) & 255)], 1);
    }
    __syncthreads();
    if (wid == 0) {
      int b0 = lane * 4;
      int t0 = 0, t1 = 0, t2 = 0, t3 = 0;
      for (int w2 = 0; w2 < 16; ++w2) {
        const int* hp2 = &histW[w2 * 256 + b0];
        t0 += hp2[0]; t1 += hp2[1]; t2 += hp2[2]; t3 += hp2[3];
      }
      int s3 = t3, s2i = t2 + s3, s1i = t1 + s2i, s0 = t0 + s1i;  // in-lane suffix
      int v = s0;
#pragma unroll
      for (int off = 1; off < 64; off <<= 1) {
        int o = __shfl_down(v, off);
        v += (lane + off < 64) ? o : 0;           // v = sum over lanes >= lane
      }
      int above = v - s0;                          // = S[b0+4]
      int S3 = above + s3, S2 = above + s2i, S1 = above + s1i, S0 = above + s0;
      if (S3 >= kneed && above < kneed)      { selb = b0 + 3; kleft = kneed - above; }
      else if (S2 >= kneed && S3 < kneed)    { selb = b0 + 2; kleft = kneed - S3; }
      else if (S1 >= kneed && S2 < kneed)    { selb = b0 + 1; kleft = kneed - S2; }
      else if (S0 >= kneed && S1 < kneed)    { selb = b0;     kleft = kneed - S1; }
    }
    __syncthreads();
    prefix = (prefix << 8) | (unsigned)selb;
    kneed = kleft;
  }
  float tau = (prefix & 0x80000000u) ? __uint_as_float(prefix & 0x7fffffffu)
                                     : __uint_as_float(~prefix);

  // tie-break lowest-index-first: 2-level scan (wave shfl + 16 wave totals)
  int cg = 0, ct = 0;
#pragma unroll
  for (int i = 0; i < 8; ++i) {
    if (sv[i] > tau) cg++;
    else if (sv[i] == tau) ct++;
  }
  int wcg = cg;
#pragma unroll
  for (int off = 32; off > 0; off >>= 1) wcg += __shfl_down(wcg, off);
  if (lane == 0) atomicAdd(&cntGt, wcg);
  int sc = ct;
#pragma unroll
  for (int off = 1; off < 64; off <<= 1) {
    int o = __shfl_up(sc, off);
    if (lane >= off) sc += o;                      // inclusive scan within wave
  }
  if (lane == 63) wtot[wid] = sc;
  __syncthreads();
  int wbase = 0;
  for (int w2 = 0; w2 < wid; ++w2) wbase += wtot[w2];
  int rank = wbase + sc - ct;                      // exclusive tie-rank in block
  int quota = KK - cntGt;

  const float4* v4r = (const float4*)v4g + (size_t)rb * NN;
  float fva[8] = {0, 0, 0, 0, 0, 0, 0, 0};
#pragma unroll
  for (int i = 0; i < 8; ++i) {
    bool inc = sv[i] > tau;
    if (!inc && sv[i] == tau) { inc = (rank < quota); rank++; }
    if (inc) {
      int n = tid * 8 + i;
      float4 vv = v4r[n];
#pragma unroll
      for (int c = 0; c < 8; ++c) {
        float h = fmaxf(vv.x * w[c] + vv.y * w[8 + c] + vv.z * w[16 + c] + vv.w * w[24 + c] + bg[c], 0.0f);
        float hn = (h - muf) * rstd * lw[c] + lb[c];
        fva[c] += hn * sv[i];
      }
    }
  }
#pragma unroll
  for (int c = 0; c < 8; ++c) atomicAdd(&fvSum[c], fva[c]);
  __syncthreads();

  size_t fo = (size_t)rb * 19;
  if (tid < 8) {
    feats[fo + tid] = ((chS[tid] - (float)NN * muf) * rstd * lw[tid]) / (float)NN + lb[tid];
    feats[fo + 8 + tid] = fvSum[tid] / (float)KK;
  }
  if (tid >= 16 && tid < 19) {
    feats[fo + tid] = cen[(size_t)rb * 3 + (tid - 16)];
  }
}

// ---------------- super graph: GAT1 -> LN -> GAT2 -> LN -> pool -> linear ----------------
__global__ __launch_bounds__(256)
void super_kernel(const float* __restrict__ feats,
                  const float* __restrict__ W1, const float* __restrict__ as1,
                  const float* __restrict__ ad1, const float* __restrict__ b1,
                  const float* __restrict__ lnw1, const float* __restrict__ lnb1,
                  const float* __restrict__ W2, const float* __restrict__ as2,
                  const float* __restrict__ ad2, const float* __restrict__ b2,
                  const float* __restrict__ lnw2, const float* __restrict__ lnb2,
                  const float* __restrict__ linw, const float* __restrict__ linb,
                  float* __restrict__ out) {
  __shared__ float sx[NSUP * 19];
  __shared__ float h1[NSUP * 64];
  __shared__ float x1[NSUP * 64];
  __shared__ float es1[NSUP * 4], ed1[NSUP * 4];
  __shared__ float h2[NSUP * 16], x2[NSUP * 16];
  __shared__ float es2[NSUP], ed2[NSUP];
  __shared__ float stat[16];
  const int tid = threadIdx.x;

  for (int i = tid; i < NSUP * 19; i += 256) {
    int n = i / 19, c = i % 19;
    int bb = n / RR, rr = n % RR;
    sx[i] = feats[(size_t)(rr * BB + bb) * 19 + c];
  }
  __syncthreads();
  for (int p = tid; p < NSUP * 64; p += 256) {
    int n = p / 64, j = p % 64;
    float acc = 0.f;
    for (int k2 = 0; k2 < 19; ++k2) acc += sx[n * 19 + k2] * W1[k2 * 64 + j];
    h1[p] = acc;
  }
  __syncthreads();
  for (int p = tid; p < NSUP * 4; p += 256) {
    int n = p / 4, hd = p % 4;
    float a = 0.f, d2 = 0.f;
    for (int o = 0; o < 16; ++o) {
      float hv = h1[n * 64 + hd * 16 + o];
      a += hv * as1[hd * 16 + o];
      d2 += hv * ad1[hd * 16 + o];
    }
    es1[p] = a; ed1[p] = d2;
  }
  __syncthreads();
  for (int p = tid; p < NSUP * 64; p += 256) {
    int n = p / 64, j = p % 64, hd = j / 16;
    int rr = n % RR;
    float o;
    if (rr == 0) {
      o = h1[p];
    } else {
      int hub = n - rr;
      float eh = es1[hub * 4 + hd] + ed1[n * 4 + hd];
      float esf = es1[n * 4 + hd] + ed1[n * 4 + hd];
      eh = eh > 0.f ? eh : 0.2f * eh;
      esf = esf > 0.f ? esf : 0.2f * esf;
      float m = fmaxf(eh, esf);
      float wh = expf(eh - m), ws2 = expf(esf - m);
      o = (wh * h1[hub * 64 + j] + ws2 * h1[n * 64 + j]) / (wh + ws2);
    }
    float v = o + b1[j];
    x1[p] = v > 0.f ? v : expm1f(v);   // elu
  }
  __syncthreads();
  if (tid < BB) {
    double m = 0.0, v2 = 0.0;
    for (int q = 0; q < RR * 64; ++q) {
      float val = x1[tid * RR * 64 + q];
      m += val; v2 += (double)val * val;
    }
    m /= (RR * 64.0); v2 = v2 / (RR * 64.0) - m * m;
    stat[tid] = (float)m;
    stat[8 + tid] = (float)(1.0 / sqrt(v2 + 1e-5));
  }
  __syncthreads();
  for (int p = tid; p < NSUP * 64; p += 256) {
    int n = p / 64, j = p % 64, bb = n / RR;
    x1[p] = (x1[p] - stat[bb]) * stat[8 + bb] * lnw1[j] + lnb1[j];
  }
  __syncthreads();
  for (int p = tid; p < NSUP * 16; p += 256) {
    int n = p / 16, o = p % 16;
    float acc = 0.f;
    for (int j = 0; j < 64; ++j) acc += x1[n * 64 + j] * W2[j * 16 + o];
    h2[p] = acc;
  }
  __syncthreads();
  for (int n = tid; n < NSUP; n += 256) {
    float a = 0.f, d2 = 0.f;
    for (int o = 0; o < 16; ++o) {
      float hv = h2[n * 16 + o];
      a += hv * as2[o];
      d2 += hv * ad2[o];
    }
    es2[n] = a; ed2[n] = d2;
  }
  __syncthreads();
  for (int p = tid; p < NSUP * 16; p += 256) {
    int n = p / 16, o = p % 16;
    int rr = n % RR;
    float ov;
    if (rr == 0) ov = h2[p];
    else {
      int hub = n - rr;
      float eh = es2[hub] + ed2[n];
      float esf = es2[n] + ed2[n];
      eh = eh > 0.f ? eh : 0.2f * eh;
      esf = esf > 0.f ? esf : 0.2f * esf;
      float m = fmaxf(eh, esf);
      float wh = expf(eh - m), ws2 = expf(esf - m);
      ov = (wh * h2[hub * 16 + o] + ws2 * h2[p]) / (wh + ws2);
    }
    float v = ov + b2[o];
    x2[p] = v > 0.f ? v : expm1f(v);
  }
  __syncthreads();
  if (tid < BB) {
    double m = 0.0, v2 = 0.0;
    for (int q = 0; q < RR * 16; ++q) {
      float val = x2[tid * RR * 16 + q];
      m += val; v2 += (double)val * val;
    }
    m /= (RR * 16.0); v2 = v2 / (RR * 16.0) - m * m;
    stat[tid] = (float)m;
    stat[8 + tid] = (float)(1.0 / sqrt(v2 + 1e-5));
  }
  __syncthreads();
  for (int p = tid; p < NSUP * 16; p += 256) {
    int n = p / 16, o = p % 16, bb = n / RR;
    x2[p] = (x2[p] - stat[bb]) * stat[8 + bb] * lnw2[o] + lnb2[o];
  }
  __syncthreads();
  if (tid < BB * 2) {
    int bb = tid / 2, t = tid % 2;
    float acc = linb[t];
    for (int o = 0; o < 16; ++o) {
      float pm = 0.f;
      for (int rr = 0; rr < RR; ++rr) pm += x2[(bb * RR + rr) * 16 + o];
      pm /= (float)RR;
      acc += pm * linw[o * 2 + t];
    }
    out[bb * 2 + t] = acc;
  }
}

extern "C" void kernel_launch(void* const* d_in, const int* in_sizes, int n_in,
                              void* d_out, int out_size, void* d_ws, size_t ws_size,
                              hipStream_t stream) {
  const float* roi_x = (const float*)d_in[0];
  const int* ei = (const int*)d_in[1];
  const float* cen = (const float*)d_in[2];
  const float* gcn_w = (const float*)d_in[3];
  const float* gcn_b = (const float*)d_in[4];
  const float* ln_w = (const float*)d_in[5];
  const float* ln_b = (const float*)d_in[6];
  const float* topk_w = (const float*)d_in[7];
  const float* gat1_w = (const float*)d_in[8];
  const float* as1 = (const float*)d_in[9];
  const float* ad1 = (const float*)d_in[10];
  const float* b1 = (const float*)d_in[11];
  const float* lnw1 = (const float*)d_in[12];
  const float* lnb1 = (const float*)d_in[13];
  const float* W2 = (const float*)d_in[14];
  const float* as2 = (const float*)d_in[15];
  const float* ad2 = (const float*)d_in[16];
  const float* b2 = (const float*)d_in[17];
  const float* lnw2 = (const float*)d_in[18];
  const float* lnb2 = (const float*)d_in[19];
  const float* linw = (const float*)d_in[20];
  const float* linb = (const float*)d_in[21];
  float* out = (float*)d_out;

  // ws (bytes): v4g f32[80*8192*4]=10.49MB | zg f32[80*8192*4]=10.49MB | tg f32[80*8192]=2.62MB
  //  | partsS f64[1280]=10KB | partsC f32[5120]=20KB | qo8 u16[80*8192]=1.31MB | et8 i32[640]
  //  | feats f32[1520] | rank u8[80*EPB]=10.49MB | Hg u8[80*8*8192]=5.24MB  total ~40.7MB
  char* wsb = (char*)d_ws;
  float* v4g = (float*)wsb;
  float* zg = (float*)(wsb + (size_t)80 * NN * 4 * 4);
  float* tg = (float*)((char*)zg + (size_t)80 * NN * 4 * 4);
  double* partsS = (double*)((char*)tg + (size_t)80 * NN * 4);
  float* partsC = (float*)((char*)partsS + 1280 * 8);
  unsigned short* qo8 = (unsigned short*)((char*)partsC + 5120 * 4);
  int* et8 = (int*)((char*)qo8 + (size_t)80 * 8192 * 2);
  float* feats = (float*)((char*)et8 + 640 * 4);
  unsigned char* rankg = (unsigned char*)((char*)feats + (size_t)RR * BB * 19 * 4);
  unsigned char* Hg = rankg + (size_t)80 * EPB;

  count_kernel<<<640, 1024, 0, stream>>>(ei, rankg, Hg);
  merge_kernel<<<640, 1024, 0, stream>>>(Hg, roi_x, qo8, et8, zg);
  scatfuse_kernel<<<640, 512, 0, stream>>>(ei, zg, rankg, qo8, et8, Hg,
                                           gcn_w, gcn_b, ln_w, topk_w,
                                           v4g, tg, partsS, partsC);
  roiB_kernel<<<80, 1024, 0, stream>>>(tg, v4g, partsS, partsC,
                                       gcn_w, gcn_b, ln_w, ln_b, topk_w, cen, feats);
  super_kernel<<<1, 256, 0, stream>>>(feats, gat1_w, as1, ad1, b1, lnw1, lnb1,
                                      W2, as2, ad2, b2, lnw2, lnb2, linw, linb, out);
}